// Round 9
// baseline (561.315 us; speedup 1.0000x reference)
//
#include <hip/hip_runtime.h>

// Problem constants (fixed by the reference)
#define BTOT 4096
#define TB   512
#define BD   8
#define BSL  16

// LDS element map (uint16 elements, 2 B), k-major tile layout:
//   tile element (row,k) at blk*128 + row*8 + (k&7), blk = k>>3
//   -> lane (q,ln)'s A-frag (row=ln, k=ki*32+q*8+j) = 16 contiguous bytes
//      at (ki*4+q)*128 + ln*8  => ds_read_b128, 2-way banks (free).
// H0 ring (h0, depth 4): slot s at s*1024            (els 0..4095)
// H1 ring (h1, depth 4): slot s at 4096 + s*1024     (els 4096..8191)
// ZERO block (x-frag source for q>0 lanes):          (els 8192..8319)
// PROG u16 flags prog[0..7] (one per wave):          (els 8320..8327)
// XB x chunks (128 t-slots x 16 rows x 8 d):         (els 12288..28671)
//   addr = 12288 + (t & 127)*128 + row*8
#define H1R    4096
#define ZBASE  8192
#define PROGEL 8320
#define XBASE  12288
#define NLDS   28672   // 57344 B -> 1 block/CU

typedef __attribute__((ext_vector_type(8))) short  short8;  // MFMA A/B frag
typedef __attribute__((ext_vector_type(4))) float  f32x4;   // MFMA C/D frag

static __device__ __forceinline__ unsigned short f2bf(float f) {
    unsigned u = __float_as_uint(f);
    u += 0x7fffu + ((u >> 16) & 1u);
    return (unsigned short)(u >> 16);
}
static __device__ __forceinline__ float bf2f(unsigned short h) {
    return __uint_as_float(((unsigned)h) << 16);
}
static __device__ __forceinline__ unsigned pkbf(float a, float b) {
    unsigned r;  // gfx950 HW packed f32->bf16 (RNE); dest must be VGPR ("=v")
    asm("v_cvt_pk_bf16_f32 %0, %1, %2" : "=v"(r) : "v"(a), "v"(b));
    return r;
}
// min of 4 u16 counters packed in two dwords
static __device__ __forceinline__ unsigned min4h(unsigned a, unsigned b) {
    const unsigned m1 = min(a & 0xffffu, a >> 16);
    const unsigned m2 = min(b & 0xffffu, b >> 16);
    return min(m1, m2);
}

// Joint-denominator gate math: 7 trans/unit (5 exp2 + 2 rcp) — R7-verified.
static __device__ __forceinline__ void gates4(
    const f32x4 ai, const f32x4 af, const f32x4 ag, const f32x4 ao,
    float cc[4], unsigned hp[2])
{
    float h[4];
    #pragma unroll
    for (int r = 0; r < 4; ++r) {
        const float ei = __builtin_amdgcn_exp2f(ai[r]);
        const float ef = __builtin_amdgcn_exp2f(af[r]);
        const float eg = __builtin_amdgcn_exp2f(ag[r]);
        const float eo = __builtin_amdgcn_exp2f(ao[r]);
        const float Ai = 1.f + ei, Af = 1.f + ef, Ag = 1.f + eg, Ao = 1.f + eo;
        const float P = Ai * Ag;
        const float numer = cc[r] * P + Af * (eg - 1.f);
        const float rD = __builtin_amdgcn_rcpf(Af * P);
        cc[r] = numer * rD;
        const float ec = __builtin_amdgcn_exp2f(2.88539008f * cc[r]);
        const float rH = __builtin_amdgcn_rcpf(Ao * (ec + 1.f));
        h[r] = (ec - 1.f) * rH;
    }
    hp[0] = pkbf(h[0], h[1]); hp[1] = pkbf(h[2], h[3]);
}

__global__ __launch_bounds__(512, 2) void lstm2_fused(
    const float* __restrict__ x,
    const float* __restrict__ Wih0, const float* __restrict__ Whh0,
    const float* __restrict__ bih0, const float* __restrict__ bhh0,
    const float* __restrict__ Wih1, const float* __restrict__ Whh1,
    const float* __restrict__ bih1, const float* __restrict__ bhh1,
    const float* __restrict__ Wfc,  const float* __restrict__ bfc,
    float* __restrict__ out)
{
    __shared__ __align__(16) unsigned short lds16[NLDS];

    const int tid  = threadIdx.x;
    const int wid  = tid >> 6;           // 8 waves: 0..3 = layer 0, 4..7 = layer 1
    const int lane = tid & 63;
    const int q    = lane >> 4;
    const int ln   = lane & 15;
    const int rb   = blockIdx.x * BSL;

    const bool L1w = (wid >= 4);
    const int  g   = L1w ? (wid - 4) : wid;
    const int  jc  = g * 16 + ln;

    // ---- Weight fragments -> registers, bf16, exp2-scale pre-folded ----
    const float SCI = -1.44269504f;
    const float SCG =  2.88539008f;
    short8 Bf[4][4];
    #pragma unroll
    for (int G = 0; G < 4; ++G) {
        const int n = G * 64 + jc;
        const float sc = (G == 2) ? SCG : SCI;
        #pragma unroll
        for (int ki = 0; ki < 4; ++ki) {
            union { unsigned short u[8]; short8 v; } t;
            #pragma unroll
            for (int j = 0; j < 8; ++j) {
                const int k = ki * 32 + q * 8 + j;
                float wv = 0.0f;
                if (!L1w) {
                    if (ki < 3) {
                        if (k < 64)      wv = Whh0[n * 64 + k];
                        else if (k < 72) wv = Wih0[n * 8 + (k - 64)];
                    }
                } else {
                    if (k < 64)          wv = Wih1[n * 64 + k];
                    else                 wv = Whh1[n * 64 + (k - 64)];
                }
                t.u[j] = f2bf(sc * wv);
            }
            Bf[G][ki] = t.v;
        }
    }
    f32x4 biasv[4];
    #pragma unroll
    for (int G = 0; G < 4; ++G) {
        const int n = G * 64 + jc;
        const float sc = (G == 2) ? SCG : SCI;
        const float b = sc * (L1w ? (bih1[n] + bhh1[n]) : (bih0[n] + bhh0[n]));
        biasv[G] = (f32x4){b, b, b, b};
    }

    // ---- Prologue zero: DISJOINT writers (R8 bug: the tid<72 zero-loop
    //      overlapped the PROG dwords and raced the L1 seed -> deadlock) ----
    {
        unsigned* z = (unsigned*)lds16;
        z[1536 + tid] = 0;                  // h0 slot 3 (els 3072..4095)
        z[3584 + tid] = 0;                  // h1 slot 3 (els 7168..8191)
        if (tid < 64) z[4096 + tid] = 0;    // ZERO blk only (els 8192..8319)
        if (tid < 4)                        // PROG dwords: single writer each
            z[4160 + tid] = (tid >= 2) ? 0x00010001u : 0u;  // L1 seeded "done 0"
    }
    // stage x chunk 0: L0 threads, 32 floats each
    const int srow = (tid >> 4) & 15, su = tid & 15;
    if (tid < 256) {
        const float* gp = x + (size_t)(rb + srow) * (TB * BD) + (su * 4) * BD;
        float4 v[8];
        #pragma unroll
        for (int i = 0; i < 8; ++i) v[i] = ((const float4*)gp)[i];
        #pragma unroll
        for (int tt = 0; tt < 4; ++tt) {
            uint4 s;
            s.x = pkbf(v[tt*2].x, v[tt*2].y);   s.y = pkbf(v[tt*2].z, v[tt*2].w);
            s.z = pkbf(v[tt*2+1].x, v[tt*2+1].y); s.w = pkbf(v[tt*2+1].z, v[tt*2+1].w);
            *(uint4*)(lds16 + XBASE + (su * 4 + tt) * 128 + srow * 8) = s;
        }
    }
    __syncthreads();

    const int rbase = q * 128 + ln * 8;
    const int wb    = (jc >> 3) * 128 + q * 32 + (jc & 7);
    const int ln8   = ln * 8;
    volatile unsigned* pr = (volatile unsigned*)(lds16 + PROGEL);

    float cc[4] = {0.f, 0.f, 0.f, 0.f};

    if (!L1w) {
        // =============== LAYER 0: intervals 0..511 ===============
        float4 px[8];
        for (int it = 0; it < TB; ++it) {
            const int ph = it & 63;
            if (ph == 48 && it + 16 < TB) {      // prefetch next chunk -> regs
                const int t0 = (it & ~63) + 64;
                const float* gp = x + (size_t)(rb + srow) * (TB * BD) + (t0 + su * 4) * BD;
                #pragma unroll
                for (int i = 0; i < 8; ++i) px[i] = ((const float4*)gp)[i];
            }
            if (ph == 62 && it + 2 < TB) {       // pack + LDS write
                const int t0 = (it & ~63) + 64;
                #pragma unroll
                for (int tt = 0; tt < 4; ++tt) {
                    uint4 s;
                    s.x = pkbf(px[tt*2].x, px[tt*2].y);     s.y = pkbf(px[tt*2].z, px[tt*2].w);
                    s.z = pkbf(px[tt*2+1].x, px[tt*2+1].y); s.w = pkbf(px[tt*2+1].z, px[tt*2+1].w);
                    *(uint4*)(lds16 + XBASE + ((t0 & 127) + su * 4 + tt) * 128 + srow * 8) = s;
                }
            }
            // wait: all L0 done it-1 (prog>=it); all L1 done it-3 (prog>=it-2)
            {
                const unsigned tg0 = (unsigned)it;
                const unsigned tg1 = (it >= 2) ? (unsigned)(it - 2) : 0u;
                while (true) {
                    const unsigned p0 = pr[0], p1 = pr[1], p2 = pr[2], p3 = pr[3];
                    if (min4h(p0, p1) >= tg0 && min4h(p2, p3) >= tg1) break;
                }
                asm volatile("" ::: "memory");
            }
            const int rs = ((it + 3) & 3) << 10;          // h0(it-1) slot
            const short8 a0 = *(const short8*)(lds16 + rs + rbase);
            const short8 a1 = *(const short8*)(lds16 + rs + rbase + 512);
            const int xaddr = (q == 0) ? (XBASE + ((it & 127) << 7) + ln8) : (ZBASE + ln8);
            const short8 a2 = *(const short8*)(lds16 + xaddr);

            f32x4 ai = __builtin_amdgcn_mfma_f32_16x16x32_bf16(a0, Bf[0][0], biasv[0], 0, 0, 0);
            f32x4 af = __builtin_amdgcn_mfma_f32_16x16x32_bf16(a0, Bf[1][0], biasv[1], 0, 0, 0);
            f32x4 ag = __builtin_amdgcn_mfma_f32_16x16x32_bf16(a0, Bf[2][0], biasv[2], 0, 0, 0);
            f32x4 ao = __builtin_amdgcn_mfma_f32_16x16x32_bf16(a0, Bf[3][0], biasv[3], 0, 0, 0);
            ai = __builtin_amdgcn_mfma_f32_16x16x32_bf16(a1, Bf[0][1], ai, 0, 0, 0);
            af = __builtin_amdgcn_mfma_f32_16x16x32_bf16(a1, Bf[1][1], af, 0, 0, 0);
            ag = __builtin_amdgcn_mfma_f32_16x16x32_bf16(a1, Bf[2][1], ag, 0, 0, 0);
            ao = __builtin_amdgcn_mfma_f32_16x16x32_bf16(a1, Bf[3][1], ao, 0, 0, 0);
            ai = __builtin_amdgcn_mfma_f32_16x16x32_bf16(a2, Bf[0][2], ai, 0, 0, 0);
            af = __builtin_amdgcn_mfma_f32_16x16x32_bf16(a2, Bf[1][2], af, 0, 0, 0);
            ag = __builtin_amdgcn_mfma_f32_16x16x32_bf16(a2, Bf[2][2], ag, 0, 0, 0);
            ao = __builtin_amdgcn_mfma_f32_16x16x32_bf16(a2, Bf[3][2], ao, 0, 0, 0);

            unsigned hp[2];
            gates4(ai, af, ag, ao, cc, hp);
            const int ws = (it & 3) << 10;                // h0(it) slot
            lds16[ws + wb]      = (unsigned short)hp[0];
            lds16[ws + wb + 8]  = (unsigned short)(hp[0] >> 16);
            lds16[ws + wb + 16] = (unsigned short)hp[1];
            lds16[ws + wb + 24] = (unsigned short)(hp[1] >> 16);
            __threadfence_block();
            if (lane == 0)
                *(volatile unsigned short*)(lds16 + PROGEL + wid) = (unsigned short)(it + 1);
        }
    } else {
        // =============== LAYER 1: intervals 1..512 (t1 = it-1) ===============
        for (int it = 1; it <= TB; ++it) {
            {
                const unsigned tg = (unsigned)it;
                while (true) {
                    const unsigned p0 = pr[0], p1 = pr[1], p2 = pr[2], p3 = pr[3];
                    if (min4h(p0, p1) >= tg && min4h(p2, p3) >= tg) break;
                }
                asm volatile("" ::: "memory");
            }
            const int rs0 = ((it + 3) & 3) << 10;         // h0(it-1) slot
            const int rs1 = H1R + (((it + 2) & 3) << 10); // h1(it-2) slot
            const short8 a0 = *(const short8*)(lds16 + rs0 + rbase);
            const short8 a1 = *(const short8*)(lds16 + rs0 + rbase + 512);
            const short8 a2 = *(const short8*)(lds16 + rs1 + rbase);
            const short8 a3 = *(const short8*)(lds16 + rs1 + rbase + 512);

            f32x4 ai = __builtin_amdgcn_mfma_f32_16x16x32_bf16(a0, Bf[0][0], biasv[0], 0, 0, 0);
            f32x4 af = __builtin_amdgcn_mfma_f32_16x16x32_bf16(a0, Bf[1][0], biasv[1], 0, 0, 0);
            f32x4 ag = __builtin_amdgcn_mfma_f32_16x16x32_bf16(a0, Bf[2][0], biasv[2], 0, 0, 0);
            f32x4 ao = __builtin_amdgcn_mfma_f32_16x16x32_bf16(a0, Bf[3][0], biasv[3], 0, 0, 0);
            ai = __builtin_amdgcn_mfma_f32_16x16x32_bf16(a1, Bf[0][1], ai, 0, 0, 0);
            af = __builtin_amdgcn_mfma_f32_16x16x32_bf16(a1, Bf[1][1], af, 0, 0, 0);
            ag = __builtin_amdgcn_mfma_f32_16x16x32_bf16(a1, Bf[2][1], ag, 0, 0, 0);
            ao = __builtin_amdgcn_mfma_f32_16x16x32_bf16(a1, Bf[3][1], ao, 0, 0, 0);
            ai = __builtin_amdgcn_mfma_f32_16x16x32_bf16(a2, Bf[0][2], ai, 0, 0, 0);
            af = __builtin_amdgcn_mfma_f32_16x16x32_bf16(a2, Bf[1][2], af, 0, 0, 0);
            ag = __builtin_amdgcn_mfma_f32_16x16x32_bf16(a2, Bf[2][2], ag, 0, 0, 0);
            ao = __builtin_amdgcn_mfma_f32_16x16x32_bf16(a2, Bf[3][2], ao, 0, 0, 0);
            ai = __builtin_amdgcn_mfma_f32_16x16x32_bf16(a3, Bf[0][3], ai, 0, 0, 0);
            af = __builtin_amdgcn_mfma_f32_16x16x32_bf16(a3, Bf[1][3], af, 0, 0, 0);
            ag = __builtin_amdgcn_mfma_f32_16x16x32_bf16(a3, Bf[2][3], ag, 0, 0, 0);
            ao = __builtin_amdgcn_mfma_f32_16x16x32_bf16(a3, Bf[3][3], ao, 0, 0, 0);

            unsigned hp[2];
            gates4(ai, af, ag, ao, cc, hp);
            const int ws = H1R + (((it + 3) & 3) << 10);  // h1(it-1) slot
            lds16[ws + wb]      = (unsigned short)hp[0];
            lds16[ws + wb + 8]  = (unsigned short)(hp[0] >> 16);
            lds16[ws + wb + 16] = (unsigned short)hp[1];
            lds16[ws + wb + 24] = (unsigned short)(hp[1] >> 16);
            __threadfence_block();
            if (lane == 0)
                *(volatile unsigned short*)(lds16 + PROGEL + wid) = (unsigned short)(it + 1);
        }
    }

    __syncthreads();   // single epilogue barrier (all waves, equal count)

    // Final FC: h1(511) in H1 ring slot 3
    if (tid < BSL) {
        float s = bfc[0];
        #pragma unroll 8
        for (int j = 0; j < 64; ++j)
            s += bf2f(lds16[H1R + 3072 + (j >> 3) * 128 + tid * 8 + (j & 7)]) * Wfc[j];
        out[rb + tid] = s;
    }
}

extern "C" void kernel_launch(void* const* d_in, const int* in_sizes, int n_in,
                              void* d_out, int out_size, void* d_ws, size_t ws_size,
                              hipStream_t stream) {
    const float* x    = (const float*)d_in[0];
    const float* Wih0 = (const float*)d_in[1];
    const float* Whh0 = (const float*)d_in[2];
    const float* bih0 = (const float*)d_in[3];
    const float* bhh0 = (const float*)d_in[4];
    const float* Wih1 = (const float*)d_in[5];
    const float* Whh1 = (const float*)d_in[6];
    const float* bih1 = (const float*)d_in[7];
    const float* bhh1 = (const float*)d_in[8];
    const float* Wfc  = (const float*)d_in[9];
    const float* bfc  = (const float*)d_in[10];
    float* out = (float*)d_out;

    dim3 grid(BTOT / BSL);   // 256 blocks = 1 per CU
    dim3 block(512);         // 8 waves: 4 L0 + 4 L1, flag-synced (skew <= 2)
    lstm2_fused<<<grid, block, 0, stream>>>(x, Wih0, Whh0, bih0, bhh0,
                                            Wih1, Whh1, bih1, bhh1, Wfc, bfc, out);
}